// Round 8
// baseline (100.159 us; speedup 1.0000x reference)
//
#include <hip/hip_runtime.h>
#include <math.h>

// Problem constants (fixed by reference: inp (4,16,32,32) f32, weight (64,144) f32)
constexpr int F_IN   = 144;   // 16 ch * 9 taps
constexpr int F_OUT  = 64;
constexpr int H_IMG  = 32;
constexpr int W_IMG  = 32;
constexpr int NPIX   = 4 * H_IMG * W_IMG;  // 4096
constexpr int PPB    = 8;                  // pixels per block (1 wave each)
constexpr int NTHR   = PPB * 64;           // 512
#define MAX_SPIKE 100.0f

// ---------------------------------------------------------------------------
// ROUND-12: dedicated high-MLP PREFETCH between quant and spike.
// Evidence: spike is 20.5us warm (r6, after probe touched inp+wq everywhere)
// vs 38-42us cold (r0/r2/r3/r4/r7, all structures). The 256MiB poison fill
// re-colds L2/L3 every iteration. Replication (r7) falsified slice
// contention; global-wq (r3) falsified the staging path; so the delta is
// exposed cold-miss LATENCY inside a low-MLP kernel. Fix: a pure-streaming
// prefetch kernel (1 block/CU, independent float4 loads, no deps/barriers)
// pulls inp+wq into every XCD's L2; spike then runs in its warm regime.
// quant + spike are round-0 verbatim (absmax 0.00390625 preserved).
// ---------------------------------------------------------------------------
__global__ __launch_bounds__(256) void quant_kernel(
    const float* __restrict__ w,
    float* __restrict__ wqT)   // (144,64) transposed
{
#pragma clang fp contract(off)
    __shared__ float wred[4];
    const int tid = threadIdx.x;

    float m = 0.f;
    {
        const float4* w4 = (const float4*)w;
        for (int i = tid; i < (F_OUT * F_IN) / 4; i += 256) {
            const float4 v = w4[i];
            m = fmaxf(m, fmaxf(fmaxf(fabsf(v.x), fabsf(v.y)),
                               fmaxf(fabsf(v.z), fabsf(v.w))));
        }
    }
    for (int s = 32; s > 0; s >>= 1)
        m = fmaxf(m, __shfl_xor(m, s, 64));
    if ((tid & 63) == 0) wred[tid >> 6] = m;
    __syncthreads();
    const float mw = fmaxf(fmaxf(wred[0], wred[1]), fmaxf(wred[2], wred[3]));
    const float alpha = tanhf(mw);

    const int i = blockIdx.x * 256 + tid;   // 36*256 = 9216 exactly
    const int o = i / F_IN;
    const int f = i - o * F_IN;
    const float t = tanhf(w[i]);
    float x = t / alpha;                       // f32 divide (mirrors np)
    x = fminf(fmaxf(x, -1.f), 1.f) * 127.f;    // clip then *qmax
    const float r = rintf(x);                  // round half-to-even
    wqT[f * F_OUT + o] = r * alpha / 127.f;    // mul then div (mirrors np)
}

// ---------------------------------------------------------------------------
// Prefetch: every CU streams inp (16384 float4) + wq (2304 float4) with
// maximal MLP. Reads fill the local XCD's L2 with clean copies. The asm
// keep-alive prevents DCE (skill rule #17). No side effects.
// ---------------------------------------------------------------------------
__global__ __launch_bounds__(256) void prefetch_kernel(
    const float* __restrict__ inp,
    const float* __restrict__ wq)
{
    const int tid = threadIdx.x;
    float acc = 0.f;
    const float4* i4 = (const float4*)inp;     // 65536/4 = 16384
    for (int i = tid; i < 16384; i += 256) {
        const float4 v = i4[i];
        acc += v.x + v.y + v.z + v.w;
    }
    const float4* w4 = (const float4*)wq;      // 9216/4 = 2304
    for (int i = tid; i < 2304; i += 256) {
        const float4 v = w4[i];
        acc += v.x + v.y + v.z + v.w;
    }
    asm volatile("" :: "v"(acc));              // keep loads live, no store
}

// ---------------------------------------------------------------------------
// Spike conv: ROUND-0 VERBATIM (validated, absmax 0.00390625).
// ---------------------------------------------------------------------------
__global__ __launch_bounds__(NTHR, 4) void spike_conv_kernel(
    const float* __restrict__ inp,   // (4,16,32,32)
    const float* __restrict__ wq,    // (144,64)
    float* __restrict__ out)         // (4,64,32,32)
{
#pragma clang fp contract(off)
    __shared__ __align__(16) float wql[F_IN * F_OUT];          // 36 KB
    __shared__ __align__(16) unsigned long long kr[PPB][F_IN]; // 9 KB
    __shared__ float sv[PPB][F_IN + 1];                        // 4.5 KB

    const int tid  = threadIdx.x;
    const int lane = tid & 63;
    const int wv_i = tid >> 6;                   // wave id = pixel-in-block
    const int p    = blockIdx.x * PPB + wv_i;    // pixel id
    const int b    = p >> 10;
    const int l    = p & 1023;
    const int h    = l >> 5;
    const int w    = l & 31;

    // ---- async stage wq -> LDS: 36 chunks of 1 KB (64 lanes x 16 B) ----
    for (int c = wv_i; c < 36; c += PPB) {
        const float* g = wq + c * 256 + lane * 4;
        __builtin_amdgcn_global_load_lds(
            (const __attribute__((address_space(1))) void*)g,
            (__attribute__((address_space(3))) void*)&wql[c * 256],
            16, 0, 0);
    }

    // ---- stage patch, build keys (feature f = c*9 + kh*3 + kw) ----
    float v0f, v1f, v2f;
    unsigned long long key0, key1, key2;
    {
        int idx[3] = { lane, lane + 64, lane + 128 };
        float vals[3];
        for (int m = 0; m < 3; ++m) {
            const int i = idx[m];
            float v = MAX_SPIKE;
            if (i < F_IN) {
                const int c  = i / 9;
                const int r  = i - c * 9;
                const int kh = r / 3;
                const int kw = r - kh * 3;
                const int hh = h + kh - 1;
                const int ww = w + kw - 1;
                float x = 0.f;
                if (hh >= 0 && hh < H_IMG && ww >= 0 && ww < W_IMG)
                    x = inp[((b * 16 + c) * H_IMG + hh) * W_IMG + ww];
                v = (x < 0.1f) ? MAX_SPIKE : x;
                kr[wv_i][i] = ((unsigned long long)__float_as_uint(v) << 8)
                              | (unsigned)i;
            }
            vals[m] = v;
        }
        v0f = vals[0]; v1f = vals[1]; v2f = vals[2];
        key0 = ((unsigned long long)__float_as_uint(v0f) << 8) | (unsigned)idx[0];
        key1 = ((unsigned long long)__float_as_uint(v1f) << 8) | (unsigned)idx[1];
        key2 = ((unsigned long long)__float_as_uint(v2f) << 8) | (unsigned)idx[2];
        if (lane == 0) sv[wv_i][F_IN] = 1.0f;    // causality sentinel
    }
    // kr/sv wave-private: same-wave DS ordering is in-order -> no barrier.

    // ---- rank sort (keys unique -> strict < == exact stable permutation) ----
    int r0 = 0, r1 = 0, r2 = 0;
    {
        const ulonglong2* ks2 = (const ulonglong2*)&kr[wv_i][0];
#pragma unroll 4
        for (int j = 0; j < F_IN / 2; ++j) {
            const ulonglong2 kk = ks2[j];   // wave-broadcast read: conflict-free
            r0 += (kk.x < key0) + (kk.y < key0);
            r1 += (kk.x < key1) + (kk.y < key1);
            r2 += (kk.x < key2) + (kk.y < key2);
        }
    }

    // ---- scatter sorted values + record-lo (wq LDS row word offset) ----
    {
        unsigned* krlo = (unsigned*)&kr[wv_i][0];   // little-endian: lo at +0
        sv[wv_i][r0] = v0f;  krlo[2 * r0] = (unsigned)lane << 6;
        sv[wv_i][r1] = v1f;  krlo[2 * r1] = (unsigned)(lane + 64) << 6;
        if (lane < F_IN - 128) {
            sv[wv_i][r2] = v2f;  krlo[2 * r2] = (unsigned)(lane + 128) << 6;
        }
    }

    // ---- record-hi = bits of next sorted value ----
    {
        unsigned* krhi = (unsigned*)&kr[wv_i][0];
        for (int k = lane; k < F_IN; k += 64)
            krhi[2 * k + 1] = __float_as_uint(sv[wv_i][k + 1]);
    }

    // ONE block barrier: wql visible to all waves + async vmcnt drained.
    __syncthreads();

    // ---- batched scan: first valid spike == min ----
    float s   = sv[wv_i][0];
    float ws  = 0.f;
    float iws = 0.f;
    float mn  = MAX_SPIKE;      // masked / never-valid lanes => exactly 100
    bool  done = false;
    const ulonglong2* rec2 = (const ulonglong2*)&kr[wv_i][0];
    for (int k0 = 0; k0 < F_IN; k0 += 8) {
        if (s >= MAX_SPIKE) break;            // sorted: rest contribute 100
        const ulonglong2 ra = rec2[(k0 >> 1) + 0];
        const ulonglong2 rb = rec2[(k0 >> 1) + 1];
        const ulonglong2 rc = rec2[(k0 >> 1) + 2];
        const ulonglong2 rd = rec2[(k0 >> 1) + 3];
        const unsigned long long r8[8] = { ra.x, ra.y, rb.x, rb.y,
                                           rc.x, rc.y, rd.x, rd.y };
        float su[8], nx[8], wsu[8], iwsu[8];
#pragma unroll
        for (int u = 0; u < 8; ++u) {
            su[u] = s;
            nx[u] = __uint_as_float((unsigned)(r8[u] >> 32));
            const float wvv = wql[(unsigned)r8[u] + lane];  // 2-way bank: free
            ws += wvv;
            const float prod = su[u] * wvv;   // separate rounding (no FMA)
            iws += prod;
            wsu[u]  = ws;
            iwsu[u] = iws;
            s = nx[u];
        }
        // wq >= 0 => ws monotone: if last ws of batch < 1 for all lanes, the
        // whole batch is masked (contributes exactly 100) -> skip div/compares.
        if (!__all(wsu[7] < 1.0f)) {
#pragma unroll
            for (int u = 0; u < 8; ++u) {
                const float d = fmaxf(wsu[u] - 1.0f, 1e-10f); // upper clamp never binds
                const float q = iwsu[u] / d;                  // IEEE f32 divide
                const bool valid = (wsu[u] >= 1.0f) & (q >= su[u]) & (q <= nx[u]);
                if (valid & !done) { mn = q; done = true; }
            }
            if (__all(done)) break;           // windows increase: first = min
        }
    }
    out[(b * F_OUT + lane) * 1024 + l] = mn;
}

extern "C" void kernel_launch(void* const* d_in, const int* in_sizes, int n_in,
                              void* d_out, int out_size, void* d_ws, size_t ws_size,
                              hipStream_t stream) {
    const float* inp = (const float*)d_in[0];   // 65536 elems
    const float* w   = (const float*)d_in[1];   // 9216 elems
    float* out = (float*)d_out;                 // 262144 elems
    float* wqT = (float*)d_ws;                  // 9216 floats scratch

    quant_kernel<<<36, 256, 0, stream>>>(w, wqT);
    prefetch_kernel<<<256, 256, 0, stream>>>(inp, wqT);
    spike_conv_kernel<<<NPIX / PPB, NTHR, 0, stream>>>(inp, wqT, out);
}

// Round 9
// 81.670 us; speedup vs baseline: 1.2264x; 1.2264x over previous
//
#include <hip/hip_runtime.h>
#include <math.h>

// Problem constants (fixed by reference: inp (4,16,32,32) f32, weight (64,144) f32)
constexpr int F_IN   = 144;   // 16 ch * 9 taps
constexpr int F_OUT  = 64;
constexpr int H_IMG  = 32;
constexpr int W_IMG  = 32;
constexpr int NPIX   = 4 * H_IMG * W_IMG;  // 4096
constexpr int PPB    = 16;                 // pixels per block (1 wave each) -- r13 change
constexpr int NTHR   = PPB * 64;           // 1024
#define MAX_SPIKE 100.0f

// ---------------------------------------------------------------------------
// ROUND-13: halve the cold-window fan-in. Warming is falsified (r7, r8: the
// cold-fetch cost is conserved; a dedicated toucher pays it with no compute
// to hide under). r0's structure (async staging overlapped with front-end)
// is the best found; the one untested lever is staging fan-in: PPB 8->16
// halves the number of full-wq staging copies (512->256 blocks) and the
// patch-overlap refetch, with identical per-pixel math, identical waves/CU
// (16 waves/block x 1 block = 4/SIMD, same as 2x8). LDS 63.1 KB < 64 KB cap.
// Everything else r0-verbatim (absmax 0.00390625 preserved).
// ---------------------------------------------------------------------------
__global__ __launch_bounds__(256) void quant_kernel(
    const float* __restrict__ w,
    float* __restrict__ wqT)   // (144,64) transposed
{
#pragma clang fp contract(off)
    __shared__ float wred[4];
    const int tid = threadIdx.x;

    float m = 0.f;
    {
        const float4* w4 = (const float4*)w;
        for (int i = tid; i < (F_OUT * F_IN) / 4; i += 256) {
            const float4 v = w4[i];
            m = fmaxf(m, fmaxf(fmaxf(fabsf(v.x), fabsf(v.y)),
                               fmaxf(fabsf(v.z), fabsf(v.w))));
        }
    }
    for (int s = 32; s > 0; s >>= 1)
        m = fmaxf(m, __shfl_xor(m, s, 64));
    if ((tid & 63) == 0) wred[tid >> 6] = m;
    __syncthreads();
    const float mw = fmaxf(fmaxf(wred[0], wred[1]), fmaxf(wred[2], wred[3]));
    const float alpha = tanhf(mw);

    const int i = blockIdx.x * 256 + tid;   // 36*256 = 9216 exactly
    const int o = i / F_IN;
    const int f = i - o * F_IN;
    const float t = tanhf(w[i]);
    float x = t / alpha;                       // f32 divide (mirrors np)
    x = fminf(fmaxf(x, -1.f), 1.f) * 127.f;    // clip then *qmax
    const float r = rintf(x);                  // round half-to-even
    wqT[f * F_OUT + o] = r * alpha / 127.f;    // mul then div (mirrors np)
}

// ---------------------------------------------------------------------------
// Spike conv: ROUND-0 VERBATIM except PPB=16 (256 blocks x 1024 thr).
// Staging: 36 chunks over 16 waves (waves 0-3 take 3 chunks, rest 2).
// ---------------------------------------------------------------------------
__global__ __launch_bounds__(NTHR, 4) void spike_conv_kernel(
    const float* __restrict__ inp,   // (4,16,32,32)
    const float* __restrict__ wq,    // (144,64)
    float* __restrict__ out)         // (4,64,32,32)
{
#pragma clang fp contract(off)
    __shared__ __align__(16) float wql[F_IN * F_OUT];          // 36 KB
    __shared__ __align__(16) unsigned long long kr[PPB][F_IN]; // 18 KB
    __shared__ float sv[PPB][F_IN + 1];                        // 9.1 KB

    const int tid  = threadIdx.x;
    const int lane = tid & 63;
    const int wv_i = tid >> 6;                   // wave id = pixel-in-block
    const int p    = blockIdx.x * PPB + wv_i;    // pixel id
    const int b    = p >> 10;
    const int l    = p & 1023;
    const int h    = l >> 5;
    const int w    = l & 31;

    // ---- async stage wq -> LDS: 36 chunks of 1 KB (64 lanes x 16 B) ----
    for (int c = wv_i; c < 36; c += PPB) {
        const float* g = wq + c * 256 + lane * 4;
        __builtin_amdgcn_global_load_lds(
            (const __attribute__((address_space(1))) void*)g,
            (__attribute__((address_space(3))) void*)&wql[c * 256],
            16, 0, 0);
    }

    // ---- stage patch, build keys (feature f = c*9 + kh*3 + kw) ----
    float v0f, v1f, v2f;
    unsigned long long key0, key1, key2;
    {
        int idx[3] = { lane, lane + 64, lane + 128 };
        float vals[3];
        for (int m = 0; m < 3; ++m) {
            const int i = idx[m];
            float v = MAX_SPIKE;
            if (i < F_IN) {
                const int c  = i / 9;
                const int r  = i - c * 9;
                const int kh = r / 3;
                const int kw = r - kh * 3;
                const int hh = h + kh - 1;
                const int ww = w + kw - 1;
                float x = 0.f;
                if (hh >= 0 && hh < H_IMG && ww >= 0 && ww < W_IMG)
                    x = inp[((b * 16 + c) * H_IMG + hh) * W_IMG + ww];
                v = (x < 0.1f) ? MAX_SPIKE : x;
                kr[wv_i][i] = ((unsigned long long)__float_as_uint(v) << 8)
                              | (unsigned)i;
            }
            vals[m] = v;
        }
        v0f = vals[0]; v1f = vals[1]; v2f = vals[2];
        key0 = ((unsigned long long)__float_as_uint(v0f) << 8) | (unsigned)idx[0];
        key1 = ((unsigned long long)__float_as_uint(v1f) << 8) | (unsigned)idx[1];
        key2 = ((unsigned long long)__float_as_uint(v2f) << 8) | (unsigned)idx[2];
        if (lane == 0) sv[wv_i][F_IN] = 1.0f;    // causality sentinel
    }
    // kr/sv wave-private: same-wave DS ordering is in-order -> no barrier.

    // ---- rank sort (keys unique -> strict < == exact stable permutation) ----
    int r0 = 0, r1 = 0, r2 = 0;
    {
        const ulonglong2* ks2 = (const ulonglong2*)&kr[wv_i][0];
#pragma unroll 4
        for (int j = 0; j < F_IN / 2; ++j) {
            const ulonglong2 kk = ks2[j];   // wave-broadcast read: conflict-free
            r0 += (kk.x < key0) + (kk.y < key0);
            r1 += (kk.x < key1) + (kk.y < key1);
            r2 += (kk.x < key2) + (kk.y < key2);
        }
    }

    // ---- scatter sorted values + record-lo (wq LDS row word offset) ----
    {
        unsigned* krlo = (unsigned*)&kr[wv_i][0];   // little-endian: lo at +0
        sv[wv_i][r0] = v0f;  krlo[2 * r0] = (unsigned)lane << 6;
        sv[wv_i][r1] = v1f;  krlo[2 * r1] = (unsigned)(lane + 64) << 6;
        if (lane < F_IN - 128) {
            sv[wv_i][r2] = v2f;  krlo[2 * r2] = (unsigned)(lane + 128) << 6;
        }
    }

    // ---- record-hi = bits of next sorted value ----
    {
        unsigned* krhi = (unsigned*)&kr[wv_i][0];
        for (int k = lane; k < F_IN; k += 64)
            krhi[2 * k + 1] = __float_as_uint(sv[wv_i][k + 1]);
    }

    // ONE block barrier: wql visible to all waves + async vmcnt drained.
    __syncthreads();

    // ---- batched scan: first valid spike == min ----
    float s   = sv[wv_i][0];
    float ws  = 0.f;
    float iws = 0.f;
    float mn  = MAX_SPIKE;      // masked / never-valid lanes => exactly 100
    bool  done = false;
    const ulonglong2* rec2 = (const ulonglong2*)&kr[wv_i][0];
    for (int k0 = 0; k0 < F_IN; k0 += 8) {
        if (s >= MAX_SPIKE) break;            // sorted: rest contribute 100
        const ulonglong2 ra = rec2[(k0 >> 1) + 0];
        const ulonglong2 rb = rec2[(k0 >> 1) + 1];
        const ulonglong2 rc = rec2[(k0 >> 1) + 2];
        const ulonglong2 rd = rec2[(k0 >> 1) + 3];
        const unsigned long long r8[8] = { ra.x, ra.y, rb.x, rb.y,
                                           rc.x, rc.y, rd.x, rd.y };
        float su[8], nx[8], wsu[8], iwsu[8];
#pragma unroll
        for (int u = 0; u < 8; ++u) {
            su[u] = s;
            nx[u] = __uint_as_float((unsigned)(r8[u] >> 32));
            const float wvv = wql[(unsigned)r8[u] + lane];  // 2-way bank: free
            ws += wvv;
            const float prod = su[u] * wvv;   // separate rounding (no FMA)
            iws += prod;
            wsu[u]  = ws;
            iwsu[u] = iws;
            s = nx[u];
        }
        // wq >= 0 => ws monotone: if last ws of batch < 1 for all lanes, the
        // whole batch is masked (contributes exactly 100) -> skip div/compares.
        if (!__all(wsu[7] < 1.0f)) {
#pragma unroll
            for (int u = 0; u < 8; ++u) {
                const float d = fmaxf(wsu[u] - 1.0f, 1e-10f); // upper clamp never binds
                const float q = iwsu[u] / d;                  // IEEE f32 divide
                const bool valid = (wsu[u] >= 1.0f) & (q >= su[u]) & (q <= nx[u]);
                if (valid & !done) { mn = q; done = true; }
            }
            if (__all(done)) break;           // windows increase: first = min
        }
    }
    out[(b * F_OUT + lane) * 1024 + l] = mn;
}

extern "C" void kernel_launch(void* const* d_in, const int* in_sizes, int n_in,
                              void* d_out, int out_size, void* d_ws, size_t ws_size,
                              hipStream_t stream) {
    const float* inp = (const float*)d_in[0];   // 65536 elems
    const float* w   = (const float*)d_in[1];   // 9216 elems
    float* out = (float*)d_out;                 // 262144 elems
    float* wqT = (float*)d_ws;                  // 9216 floats scratch

    quant_kernel<<<36, 256, 0, stream>>>(w, wqT);
    spike_conv_kernel<<<NPIX / PPB, NTHR, 0, stream>>>(inp, wqT, out);
}